// Round 1
// baseline (695.689 us; speedup 1.0000x reference)
//
#include <hip/hip_runtime.h>

// All2AllDenseEmbedding: out[b,s,n,:] = table[idx[b,s,n], :]
// inputs:  d_in[0] = indices, flat count = BATCH*SLOTS*NNZ = 4,259,840 (int)
//          d_in[1] = table,   flat count = VOCAB*EMB = 32,000,000 (float32)
// output:  d_out = float32, 4,259,840 * 32 = 136,314,880 elements
//
// Mapping: one float4 per thread; 8 consecutive threads copy one 32-float row.
// Writes fully coalesced; each row read is one contiguous 128B segment.

#define EMB 32
#define F4_PER_ROW (EMB / 4)  // 8

__global__ __launch_bounds__(256) void All2AllDenseEmbedding_28080496181534_kernel(
    const int* __restrict__ idx,
    const float* __restrict__ table,
    float* __restrict__ out,
    int n_lookups)
{
    long long t = (long long)blockIdx.x * blockDim.x + threadIdx.x;
    long long total = (long long)n_lookups * F4_PER_ROW;
    if (t >= total) return;

    int lookup = (int)(t >> 3);   // which embedding row
    int sub    = (int)(t & 7);    // which float4 within the row

    int row = idx[lookup];        // 8 lanes hit same cacheline -> broadcast

    const float4* src = reinterpret_cast<const float4*>(table) +
                        (long long)row * F4_PER_ROW + sub;
    float4 v = *src;

    reinterpret_cast<float4*>(out)[t] = v;   // coalesced: consecutive t -> consecutive 16B
}

extern "C" void kernel_launch(void* const* d_in, const int* in_sizes, int n_in,
                              void* d_out, int out_size, void* d_ws, size_t ws_size,
                              hipStream_t stream) {
    const int*   idx   = (const int*)d_in[0];
    const float* table = (const float*)d_in[1];
    float*       out   = (float*)d_out;

    const int n_lookups = in_sizes[0];                    // 4,259,840
    const long long total_f4 = (long long)n_lookups * F4_PER_ROW;  // 34,078,720

    const int block = 256;
    const long long grid = (total_f4 + block - 1) / block;  // 133,120 blocks

    All2AllDenseEmbedding_28080496181534_kernel<<<(unsigned)grid, block, 0, stream>>>(
        idx, table, out, n_lookups);
}

// Round 3
// 685.180 us; speedup vs baseline: 1.0153x; 1.0153x over previous
//
#include <hip/hip_runtime.h>

// All2AllDenseEmbedding: out[b,s,n,:] = table[idx[b,s,n], :]
//   d_in[0] = indices (int32 per harness), 4,259,840 elements
//   d_in[1] = table   (float32), 1,000,000 x 32 = 128 MB
//   d_out   = float32, 4,259,840 * 32 = 545 MB
//
// Strategy:
//  1) warm_table: streaming read of the table to pull all 128 MB into the
//     memory-side Infinity Cache (the harness's 2.18 GB d_out/d_ws poison
//     evicted it). Linear fill = good DRAM page locality (~20 us).
//  2) gather: 8 lanes per row (one float4/lane). Table reads hit L3;
//     output written with NONTEMPORAL stores so the 545 MB write stream
//     does not evict the table mid-pass (preserves the ~4.26x row reuse).
//
// Note: __builtin_nontemporal_store requires a clang vector type, not HIP's
// float4 class -> use ext_vector_type(4).

#define EMB 32
#define F4_PER_ROW (EMB / 4)  // 8

typedef float floatx4 __attribute__((ext_vector_type(4)));

__global__ __launch_bounds__(256) void warm_table_kernel(
    const floatx4* __restrict__ table4, long long n4)
{
    long long stride = (long long)gridDim.x * blockDim.x;
    for (long long i = (long long)blockIdx.x * blockDim.x + threadIdx.x;
         i < n4; i += stride) {
        floatx4 v = table4[i];
        // keep the load live without writing anywhere (no DCE)
        asm volatile("" :: "v"(v.x), "v"(v.y), "v"(v.z), "v"(v.w));
    }
}

__global__ __launch_bounds__(256) void All2AllDenseEmbedding_28080496181534_kernel(
    const int* __restrict__ idx,
    const float* __restrict__ table,
    float* __restrict__ out,
    int n_lookups)
{
    long long t = (long long)blockIdx.x * blockDim.x + threadIdx.x;
    long long total = (long long)n_lookups * F4_PER_ROW;
    if (t >= total) return;

    int lookup = (int)(t >> 3);   // which embedding row
    int sub    = (int)(t & 7);    // which float4 within the row

    // idx is streamed once; NT keeps it from polluting caches.
    int row = __builtin_nontemporal_load(idx + lookup);

    // Regular (caching) load: row should be L3-resident after warm pass,
    // and stays resident because the output stream below is non-temporal.
    const floatx4* src = reinterpret_cast<const floatx4*>(table) +
                         (long long)row * F4_PER_ROW + sub;
    floatx4 v = *src;

    // Non-temporal store: no-allocate in L2/L3 -> no table eviction.
    __builtin_nontemporal_store(v, reinterpret_cast<floatx4*>(out) + t);
}

extern "C" void kernel_launch(void* const* d_in, const int* in_sizes, int n_in,
                              void* d_out, int out_size, void* d_ws, size_t ws_size,
                              hipStream_t stream) {
    const int*   idx   = (const int*)d_in[0];
    const float* table = (const float*)d_in[1];
    float*       out   = (float*)d_out;

    const int n_lookups = in_sizes[0];                            // 4,259,840
    const long long table_f4 = (long long)in_sizes[1] / 4;        // 8,000,000
    const long long total_f4 = (long long)n_lookups * F4_PER_ROW; // 34,078,720

    const int block = 256;

    // 1) warm the table into the Infinity Cache (streaming, ~20 us)
    warm_table_kernel<<<2048, block, 0, stream>>>(
        reinterpret_cast<const floatx4*>(table), table_f4);

    // 2) gather with NT output stores
    const long long grid = (total_f4 + block - 1) / block;        // 133,120
    All2AllDenseEmbedding_28080496181534_kernel<<<(unsigned)grid, block, 0, stream>>>(
        idx, table, out, n_lookups);
}